// Round 8
// baseline (511.639 us; speedup 1.0000x reference)
//
#include <hip/hip_runtime.h>
#include <hip/hip_bf16.h>

// MHAHead B=8,S=2048,E=512. R8 = R7 + double-buffered (depth-1 prefetch)
// GEMM core: one __syncthreads per K-iter; global_load_lds for iter k+1
// issued right after the barrier, so the barrier's vmcnt(0) drains loads
// that had a full compute-phase to fly. Epilogue Ts tile aliases the core
// LDS buffers (dead after the K-loop) to keep 4 blocks/CU.

typedef unsigned short u16;
typedef unsigned int u32;
typedef __attribute__((ext_vector_type(8))) short short8;
typedef __attribute__((ext_vector_type(4))) float float4v;

#define S_DIM 2048
#define E_DIM 512
#define NROWS (8 * S_DIM)
#define SCALE 0.044194173824159216f
#define WB_W_U16 (3 * 262144)
#define WB_B_U16 (3 * 512)
#define FLAG_BYTE ((WB_W_U16 + WB_B_U16) * 2)

__device__ __forceinline__ float4v mfma16(short8 a, short8 b, float4v c) {
    return __builtin_amdgcn_mfma_f32_16x16x32_bf16(a, b, c, 0, 0, 0);
}
__device__ __forceinline__ float bf2f(unsigned int u) {
    union { unsigned int i; float f; } v; v.i = u << 16; return v.f;
}
__device__ __forceinline__ u16 f2bf_bits(float f) {
    __hip_bfloat16 h = __float2bfloat16(f);
    return *(u16*)&h;
}
__device__ __forceinline__ int detect_bf16(const void* wp) {
    const u16* w = (const u16*)wp;
    int cnt = 0;
    for (int i = 0; i < 64; ++i) {
        int e = (w[2 * i] >> 7) & 0xff;
        cnt += (e >= 100 && e <= 131) ? 1 : 0;
    }
    return cnt >= 40;
}
__device__ __forceinline__ void load8(const void* base, size_t idx, int isbf, float* f) {
    if (isbf) {
        uint4 v = *(const uint4*)((const u16*)base + idx);
        f[0] = bf2f(v.x & 0xffffu); f[1] = bf2f(v.x >> 16);
        f[2] = bf2f(v.y & 0xffffu); f[3] = bf2f(v.y >> 16);
        f[4] = bf2f(v.z & 0xffffu); f[5] = bf2f(v.z >> 16);
        f[6] = bf2f(v.w & 0xffffu); f[7] = bf2f(v.w >> 16);
    } else {
        const float* p = (const float*)base + idx;
        float4 a = *(const float4*)p;
        float4 b = *(const float4*)(p + 4);
        f[0] = a.x; f[1] = a.y; f[2] = a.z; f[3] = a.w;
        f[4] = b.x; f[5] = b.y; f[6] = b.z; f[7] = b.w;
    }
}
__device__ __forceinline__ float load1(const void* base, size_t idx, int isbf) {
    return isbf ? bf2f(((const u16*)base)[idx]) : ((const float*)base)[idx];
}
__device__ __forceinline__ void gld16(const u16* g, u16* l) {
    __builtin_amdgcn_global_load_lds(
        (const __attribute__((address_space(1))) void*)g,
        (__attribute__((address_space(3))) void*)l, 16, 0, 0);
}

// ---------------- conv_w ----------------
__global__ __launch_bounds__(256) void conv_w(
    const void* w0, const void* w1, const void* w2,
    const void* b0, const void* b1, const void* b2, u16* wb)
{
    const int z = blockIdx.y;
    const void* w = (z == 0) ? w0 : (z == 1) ? w1 : w2;
    const void* bb = (z == 0) ? b0 : (z == 1) ? b1 : b2;
    const int isbf = detect_bf16(w0);
    const size_t idx = ((size_t)blockIdx.x * 256 + threadIdx.x) * 8;
    float f[8];
    load8(w, idx, isbf, f);
    union { u16 h[8]; uint4 v; } pk;
#pragma unroll
    for (int j = 0; j < 8; ++j) pk.h[j] = f2bf_bits(f[j]);
    *(uint4*)(wb + (size_t)z * 262144 + idx) = pk.v;
    if (blockIdx.x == 0) {
        u16* bbase = wb + WB_W_U16 + z * 512;
#pragma unroll
        for (int j = 0; j < 2; ++j) {
            int i = threadIdx.x * 2 + j;
            bbase[i] = f2bf_bits(load1(bb, i, isbf));
        }
        if (z == 0 && threadIdx.x == 0)
            *(int*)((char*)wb + FLAG_BYTE) = isbf;
    }
}

// ---------------- conv_x ----------------
__global__ __launch_bounds__(256) void conv_x(void* xbuf, const int* flagp) {
    if (*flagp) return;
    const int w = threadIdx.x >> 6, l = threadIdx.x & 63;
    const int row = blockIdx.x * 4 + w;
    const float* src = (const float*)xbuf + (size_t)row * E_DIM + l * 8;
    float4 a = *(const float4*)src;
    float4 b = *(const float4*)(src + 4);
    union { u16 h[8]; uint4 v; } pk;
    pk.h[0] = f2bf_bits(a.x); pk.h[1] = f2bf_bits(a.y);
    pk.h[2] = f2bf_bits(a.z); pk.h[3] = f2bf_bits(a.w);
    pk.h[4] = f2bf_bits(b.x); pk.h[5] = f2bf_bits(b.y);
    pk.h[6] = f2bf_bits(b.z); pk.h[7] = f2bf_bits(b.w);
    *(uint4*)((u16*)xbuf + (size_t)row * 1024 + l * 8) = pk.v;
}

// ---------------- mask_compress ----------------
__global__ __launch_bounds__(256) void mask_compress(
    const int* __restrict__ mask, u32* __restrict__ bits,
    int mode, const int* flagp)
{
    if (mode == 1 && *flagp) return;
    const size_t widx = (size_t)blockIdx.x * 256 + threadIdx.x;
    const int* src = mask + widx * 32;
    u32 v = 0;
#pragma unroll
    for (int j = 0; j < 32; j += 4) {
        int4 m4 = *(const int4*)(src + j);
        v |= (u32)(m4.x > 0) << j;
        v |= (u32)(m4.y > 0) << (j + 1);
        v |= (u32)(m4.z > 0) << (j + 2);
        v |= (u32)(m4.w > 0) << (j + 3);
    }
    bits[widx] = v;
}

// ---------------- double-buffered GEMM core ----------------
// smem16 layout (u16 idx): As0 @0, Bs0 @4096, As1 @8192, Bs1 @12288 (32 KB).
// One __syncthreads per iter; prefetch for iter+1 issued right after it.
__device__ __forceinline__ void gemm_core_db(
    const u16* __restrict__ A, int sA, const u16* __restrict__ B, int sB, int K,
    u16* __restrict__ smem16, float4v acc[4][4])
{
    const int t = threadIdx.x;
    const int w = t >> 6, l = t & 63;
    const int lane15 = l & 15, quad = l >> 4;
    const int wm = w & 1, wn = w >> 1;

    u16* As[2] = { smem16,        smem16 + 8192 };
    u16* Bs[2] = { smem16 + 4096, smem16 + 12288 };

    const int fg0 = w * 128 + l;            // granules fg0, fg0+64
    const int r0 = fg0 >> 2,        kq0 = (fg0 & 3) ^ ((r0 >> 1) & 3);
    const int r1 = (fg0 + 64) >> 2, kq1 = ((fg0 + 64) & 3) ^ ((r1 >> 1) & 3);
    const u16* Ar0 = A + (size_t)r0 * sA + kq0 * 8;
    const u16* Br0 = B + (size_t)r0 * sB + kq0 * 8;
    const u16* Ar1 = A + (size_t)r1 * sA + kq1 * 8;
    const u16* Br1 = B + (size_t)r1 * sB + kq1 * 8;

    // prologue: stage iter 0 into buf 0
    gld16(Ar0, As[0] + fg0 * 8);
    gld16(Br0, Bs[0] + fg0 * 8);
    gld16(Ar1, As[0] + (fg0 + 64) * 8);
    gld16(Br1, Bs[0] + (fg0 + 64) * 8);

    const int NIT = K >> 5;
    for (int it = 0; it < NIT; ++it) {
        __syncthreads();          // drains buf-cur loads (issued 1 iter ago)
        const int cur = it & 1;
        if (it + 1 < NIT) {       // prefetch iter+1 into the other buffer
            const int kt = (it + 1) << 5;
            u16* An = As[cur ^ 1]; u16* Bn = Bs[cur ^ 1];
            gld16(Ar0 + kt, An + fg0 * 8);
            gld16(Br0 + kt, Bn + fg0 * 8);
            gld16(Ar1 + kt, An + (fg0 + 64) * 8);
            gld16(Br1 + kt, Bn + (fg0 + 64) * 8);
        }
        short8 af[4], bf[4];
#pragma unroll
        for (int mi = 0; mi < 4; ++mi) {
            const int r = wm * 64 + mi * 16 + lane15;
            af[mi] = *(const short8*)&As[cur][(4 * r + (quad ^ ((r >> 1) & 3))) * 8];
        }
#pragma unroll
        for (int ni = 0; ni < 4; ++ni) {
            const int r = wn * 64 + ni * 16 + lane15;
            bf[ni] = *(const short8*)&Bs[cur][(4 * r + (quad ^ ((r >> 1) & 3))) * 8];
        }
#pragma unroll
        for (int mi = 0; mi < 4; ++mi)
#pragma unroll
            for (int ni = 0; ni < 4; ++ni)
                acc[mi][ni] = mfma16(af[mi], bf[ni], acc[mi][ni]);
    }
}

// per-wave LDS redistribution -> coalesced global stores. Ts aliases the core
// LDS buffers, so a leading barrier waits for all LDS readers first.
__device__ __forceinline__ void store_tile_bf16(
    u16 (*Ts)[40], const u16 vals[4][4][4],
    int lane15, int quad, u16* gbase, size_t rstride)
{
    __syncthreads();
#pragma unroll
    for (int h = 0; h < 2; ++h) {
#pragma unroll
        for (int mi = 0; mi < 4; ++mi)
#pragma unroll
            for (int nn = 0; nn < 2; ++nn)
#pragma unroll
                for (int r = 0; r < 4; ++r)
                    Ts[mi * 16 + quad * 4 + r][nn * 16 + lane15] =
                        vals[mi][2 * h + nn][r];
        __syncthreads();
#pragma unroll
        for (int mi = 0; mi < 4; ++mi) {
            uint4 v = *(const uint4*)&Ts[mi * 16 + lane15][quad * 8];
            *(uint4*)(gbase + (size_t)(mi * 16 + lane15) * rstride +
                      h * 32 + quad * 8) = v;
        }
        __syncthreads();
    }
}

#define GEMM_IDS()                                                  \
    const int t = threadIdx.x;                                      \
    const int w = t >> 6, l = t & 63; (void)l;                      \
    const int lane15 = l & 15, quad = l >> 4;                       \
    const int wm = w & 1, wn = w >> 1;

// ---------------- proj: Q, K, Vt ----------------
__global__ __launch_bounds__(256) void proj_gemm(
    const void* __restrict__ xorig, const int* flagp,
    const u16* __restrict__ wb,
    u16* __restrict__ qb, u16* __restrict__ kb, int sQK, u16* __restrict__ vt)
{
    __shared__ u16 smem16[16384] __attribute__((aligned(16)));   // 32 KB
    GEMM_IDS();
    u16 (*Ts)[40] = (u16(*)[40])smem16 + w * 64;                 // alias

    const int z = blockIdx.z;
    const int isbf = *(const volatile int*)flagp;
    const u16* xb = (const u16*)xorig;
    const int sx = isbf ? 512 : 1024;
    const u16* bias = wb + WB_W_U16 + z * 512;

    int m0, n0; const u16 *A, *B; int sA, sB;
    if (z < 2) {
        m0 = blockIdx.y * 128; n0 = blockIdx.x * 128;
        A = xb + (size_t)m0 * sx; sA = sx;
        B = wb + (size_t)z * 262144 + (size_t)n0 * 512; sB = 512;
    } else {
        m0 = blockIdx.x * 128; n0 = blockIdx.y * 128;
        A = wb + (size_t)2 * 262144 + (size_t)m0 * 512; sA = 512;
        B = xb + (size_t)n0 * sx; sB = sx;
    }

    float bcol[4], brow[4][4];
    if (z < 2) {
#pragma unroll
        for (int ni = 0; ni < 4; ++ni)
            bcol[ni] = bf2f(bias[n0 + wn * 64 + ni * 16 + lane15]);
    } else {
#pragma unroll
        for (int mi = 0; mi < 4; ++mi)
#pragma unroll
            for (int r = 0; r < 4; ++r)
                brow[mi][r] = bf2f(bias[m0 + wm * 64 + mi * 16 + quad * 4 + r]);
    }

    float4v acc[4][4];
#pragma unroll
    for (int mi = 0; mi < 4; ++mi)
#pragma unroll
        for (int ni = 0; ni < 4; ++ni) acc[mi][ni] = (float4v){0.f, 0.f, 0.f, 0.f};

    gemm_core_db(A, sA, B, sB, 512, smem16, acc);

    u16 vals[4][4][4];
    if (z < 2) {
#pragma unroll
        for (int mi = 0; mi < 4; ++mi)
#pragma unroll
            for (int ni = 0; ni < 4; ++ni)
#pragma unroll
                for (int r = 0; r < 4; ++r)
                    vals[mi][ni][r] = f2bf_bits(acc[mi][ni][r] + bcol[ni]);
        u16* dst = (z ? kb : qb);
        store_tile_bf16(Ts, vals, lane15, quad,
                        dst + (size_t)(m0 + wm * 64) * sQK + n0 + wn * 64,
                        (size_t)sQK);
    } else {
#pragma unroll
        for (int mi = 0; mi < 4; ++mi)
#pragma unroll
            for (int ni = 0; ni < 4; ++ni)
#pragma unroll
                for (int r = 0; r < 4; ++r)
                    vals[mi][ni][r] = f2bf_bits(acc[mi][ni][r] + brow[mi][r]);
        const int b = n0 >> 11, tok0 = n0 & 2047;
        store_tile_bf16(Ts, vals, lane15, quad,
                        vt + (size_t)b * E_DIM * S_DIM +
                        (size_t)(m0 + wm * 64) * S_DIM + tok0 + wn * 64,
                        (size_t)S_DIM);
    }
}

// ---------------- gemmS ----------------
__global__ __launch_bounds__(256) void gemmS(
    const u16* __restrict__ qb, const u16* __restrict__ kb, int sQK,
    const int* __restrict__ mask, const u32* __restrict__ bits, int bits_mode,
    const int* flagp, u16* sx_base, u16* sws_base, int nx,
    float* __restrict__ spart)
{
    __shared__ u16 smem16[16384] __attribute__((aligned(16)));   // 32 KB
    __shared__ u32 Ms[128][4];
    __shared__ float Rred[128];
    GEMM_IDS();
    u16 (*Ts)[40] = (u16(*)[40])smem16 + w * 64;                 // alias

    const int b = blockIdx.z, m0 = blockIdx.y * 128, ng = blockIdx.x;
    const int use_bits = (bits_mode == 2) ||
                         (bits_mode == 1 && !*(const volatile int*)flagp);
    const u16* A = qb + (size_t)(b * S_DIM + m0) * sQK;
    u16* Sb = (b < nx) ? (sx_base + (size_t)b * S_DIM * S_DIM)
                       : (sws_base + (size_t)(b - nx) * S_DIM * S_DIM);

    float rsum[4][4] = {};

    for (int nt = 0; nt < 2; ++nt) {
        const int n0 = ng * 256 + nt * 128;
        if (use_bits && t < 128)
            gld16((const u16*)(bits + ((size_t)(b * S_DIM + m0 + t) * 64) + (n0 >> 5)),
                  (u16*)&Ms[t][0]);

        const u16* B = kb + (size_t)(b * S_DIM + n0) * sQK;
        float4v acc[4][4];
#pragma unroll
        for (int mi = 0; mi < 4; ++mi)
#pragma unroll
            for (int ni = 0; ni < 4; ++ni) acc[mi][ni] = (float4v){0.f, 0.f, 0.f, 0.f};

        gemm_core_db(A, sQK, B, sQK, 512, smem16, acc);

        u16 vals[4][4][4];
#pragma unroll
        for (int mi = 0; mi < 4; ++mi)
#pragma unroll
            for (int r = 0; r < 4; ++r) {
                const int rloc = wm * 64 + mi * 16 + quad * 4 + r;
                u32 w0 = 0, w1 = 0;
                int mkraw[4];
                if (use_bits) {
                    uint2 mw = *(const uint2*)&Ms[rloc][wn * 2];
                    w0 = mw.x; w1 = mw.y;
                } else {
#pragma unroll
                    for (int ni = 0; ni < 4; ++ni)
                        mkraw[ni] = mask[((size_t)b * S_DIM + m0 + rloc) * S_DIM +
                                         n0 + wn * 64 + ni * 16 + lane15];
                }
#pragma unroll
                for (int ni = 0; ni < 4; ++ni) {
                    int masked;
                    if (use_bits) {
                        const u32 word = (ni >> 1) ? w1 : w0;
                        masked = (word >> (((ni & 1) << 4) | lane15)) & 1;
                    } else masked = (mkraw[ni] > 0);
                    const float p = masked ? 0.f : __expf(acc[mi][ni][r] * SCALE);
                    const u16 hv = f2bf_bits(p);
                    vals[mi][ni][r] = hv;
                    rsum[mi][r] += bf2f(hv);
                }
            }
        store_tile_bf16(Ts, vals, lane15, quad,
                        Sb + (size_t)(m0 + wm * 64) * S_DIM + n0 + wn * 64,
                        (size_t)S_DIM);
    }

    // rowsum partials (butterfly under full exec)
    float vred[4][4];
#pragma unroll
    for (int mi = 0; mi < 4; ++mi)
#pragma unroll
        for (int r = 0; r < 4; ++r) {
            float v = rsum[mi][r];
            v += __shfl_xor(v, 1, 64);
            v += __shfl_xor(v, 2, 64);
            v += __shfl_xor(v, 4, 64);
            v += __shfl_xor(v, 8, 64);
            vred[mi][r] = v;
            if (wn == 0 && lane15 == 0)
                Rred[wm * 64 + mi * 16 + quad * 4 + r] = v;
        }
    __syncthreads();
    if (wn == 1 && lane15 == 0) {
#pragma unroll
        for (int mi = 0; mi < 4; ++mi)
#pragma unroll
            for (int r = 0; r < 4; ++r) {
                const int rloc = wm * 64 + mi * 16 + quad * 4 + r;
                spart[((size_t)b * S_DIM + m0 + rloc) * 8 + ng] =
                    Rred[rloc] + vred[mi][r];
            }
    }
}

// ---------------- rowsum_reduce ----------------
__global__ __launch_bounds__(256) void rowsum_reduce(
    const float* __restrict__ spart, float* __restrict__ rowtot)
{
    const int i = blockIdx.x * 256 + threadIdx.x;
    const float4 a = *(const float4*)(spart + (size_t)i * 8);
    const float4 b = *(const float4*)(spart + (size_t)i * 8 + 4);
    rowtot[i] = a.x + a.y + a.z + a.w + b.x + b.y + b.z + b.w;
}

// ---------------- gemmO ----------------
__global__ __launch_bounds__(256) void gemmO(
    const u16* sx_base, const u16* sws_base, int nx,
    const u16* __restrict__ vt, const float* __restrict__ rowtot,
    float* __restrict__ outp)
{
    __shared__ u16 smem16[16384] __attribute__((aligned(16)));   // 32 KB
    GEMM_IDS();

    const int b = blockIdx.z;
    const int m0 = blockIdx.y * 128, n0 = blockIdx.x * 128;
    const u16* Sb = (b < nx) ? (sx_base + (size_t)b * S_DIM * S_DIM)
                             : (sws_base + (size_t)(b - nx) * S_DIM * S_DIM);
    const u16* A = Sb + (size_t)m0 * S_DIM;
    const u16* B = vt + ((size_t)b * E_DIM + n0) * S_DIM;

    float rt[4][4];
#pragma unroll
    for (int mi = 0; mi < 4; ++mi)
#pragma unroll
        for (int r = 0; r < 4; ++r)
            rt[mi][r] = rowtot[b * S_DIM + m0 + wm * 64 + mi * 16 + quad * 4 + r];

    float4v acc[4][4];
#pragma unroll
    for (int mi = 0; mi < 4; ++mi)
#pragma unroll
        for (int ni = 0; ni < 4; ++ni) acc[mi][ni] = (float4v){0.f, 0.f, 0.f, 0.f};

    gemm_core_db(A, S_DIM, B, S_DIM, S_DIM, smem16, acc);

#pragma unroll
    for (int mi = 0; mi < 4; ++mi)
#pragma unroll
        for (int r = 0; r < 4; ++r) {
            const int row = m0 + wm * 64 + mi * 16 + quad * 4 + r;
            const float inv = 1.f / rt[mi][r];
#pragma unroll
            for (int ni = 0; ni < 4; ++ni)
                outp[((size_t)b * S_DIM + row) * E_DIM + n0 + wn * 64 +
                     ni * 16 + lane15] = acc[mi][ni][r] * inv;
        }
}

extern "C" void kernel_launch(void* const* d_in, const int* in_sizes, int n_in,
                              void* d_out, int out_size, void* d_ws, size_t ws_size,
                              hipStream_t stream) {
    const void* x    = d_in[0];
    const int*  mask = (const int*)d_in[1];
    const void* wq   = d_in[2];
    const void* bq   = d_in[3];
    const void* wk   = d_in[4];
    const void* bk   = d_in[5];
    const void* wv   = d_in[6];
    const void* bv   = d_in[7];

    const size_t MB      = 1u << 20;
    const size_t QSZ_B   = (size_t)NROWS * E_DIM * 2;
    const size_t S_PB_B  = (size_t)S_DIM * S_DIM * 2;
    const size_t SPART_B = (size_t)NROWS * 8 * 4;
    const size_t RTOT_B  = (size_t)NROWS * 4;
    const size_t BITS_B  = (size_t)8 * S_DIM * 64 * 4;
    const size_t BIG_NEED = 2 * MB + 3 * QSZ_B + SPART_B + RTOT_B +
                            8 * S_PB_B + BITS_B;

    u16* wb = (u16*)d_ws;
    const int* flagp = (const int*)((char*)d_ws + FLAG_BYTE);
    char* p = (char*)d_ws + 2 * MB;

    u16 *qb, *kb, *vtb, *sws; float *spart, *rowtot; u32* bits;
    u16* sx_base = (u16*)x;
    int sQK, nx, bits_mode;

    if (ws_size >= BIG_NEED) {
        qb  = (u16*)p;              p += QSZ_B;
        kb  = (u16*)p;              p += QSZ_B;
        vtb = (u16*)p;              p += QSZ_B;
        spart = (float*)p;          p += SPART_B;
        rowtot = (float*)p;         p += RTOT_B;
        sws = (u16*)p;              p += 8 * S_PB_B;
        bits = (u32*)p;
        sQK = 512; nx = 0; bits_mode = 2;
    } else {
        qb  = (u16*)d_out;
        kb  = (u16*)d_out + 512;
        vtb = (u16*)p;              p += QSZ_B;
        spart = (float*)p;          p += SPART_B;
        rowtot = (float*)p;         p += RTOT_B;
        sws = (u16*)p;
        bits = (u32*)((char*)x + 2 * S_PB_B);
        sQK = 1024; nx = 2; bits_mode = 1;
    }

    conv_w<<<dim3(128, 3), 256, 0, stream>>>(wq, wk, wv, bq, bk, bv, wb);
    conv_x<<<NROWS / 4, 256, 0, stream>>>((void*)x, flagp);

    proj_gemm<<<dim3(4, 128, 3), 256, 0, stream>>>(x, flagp, wb, qb, kb, sQK, vtb);

    mask_compress<<<4096, 256, 0, stream>>>(mask, bits, bits_mode, flagp);

    gemmS<<<dim3(8, 16, 8), 256, 0, stream>>>(qb, kb, sQK, mask, bits, bits_mode,
                                              flagp, sx_base, sws, nx, spart);

    rowsum_reduce<<<NROWS / 256, 256, 0, stream>>>(spart, rowtot);

    gemmO<<<dim3(4, 16, 8), 256, 0, stream>>>(sx_base, sws, nx, vtb, rowtot,
                                              (float*)d_out);
}

// Round 9
// 483.889 us; speedup vs baseline: 1.0573x; 1.0573x over previous
//
#include <hip/hip_runtime.h>
#include <hip/hip_bf16.h>

// MHAHead B=8,S=2048,E=512. R9: revert R8 dbuf (regressed); R7 cores.
// Big-ws mode uses the G-trick: S = XG·xb^T + r_i + s_j + c where
// G' = Wk^T·Wq, XG = xb@G'^T, u=Wq^T bk, v=Wk^T bq, c=bq·bk,
// r_i = x_i·u + c, s_j = x_j·v  -> K projection eliminated.
// Small-ws mode keeps the R7 3-proj pipeline/layout exactly.
// gemmO inlines the rowsum reduction (kernel dropped).

typedef unsigned short u16;
typedef unsigned int u32;
typedef __attribute__((ext_vector_type(8))) short short8;
typedef __attribute__((ext_vector_type(4))) float float4v;

#define S_DIM 2048
#define E_DIM 512
#define NROWS (8 * S_DIM)
#define SCALE 0.044194173824159216f

// ws prep-region byte offsets
#define FLAG_B  1575936            // after 3 weights (1.5MB) + 3 biases
#define GP_B    1576960            // G' bf16 512x512
#define U_B     2101248            // float[512]
#define V_B     2103296            // float[512]
#define C_B     2105344            // float
#define R_B     2105408            // float[16384]
#define SS_B    2170944            // float[16384]
#define PREP_B  4194304            // 4 MB region

__device__ __forceinline__ float4v mfma16(short8 a, short8 b, float4v c) {
    return __builtin_amdgcn_mfma_f32_16x16x32_bf16(a, b, c, 0, 0, 0);
}
__device__ __forceinline__ float bf2f(unsigned int u) {
    union { unsigned int i; float f; } v; v.i = u << 16; return v.f;
}
__device__ __forceinline__ u16 f2bf_bits(float f) {
    __hip_bfloat16 h = __float2bfloat16(f);
    return *(u16*)&h;
}
__device__ __forceinline__ int detect_bf16(const void* wp) {
    const u16* w = (const u16*)wp;
    int cnt = 0;
    for (int i = 0; i < 64; ++i) {
        int e = (w[2 * i] >> 7) & 0xff;
        cnt += (e >= 100 && e <= 131) ? 1 : 0;
    }
    return cnt >= 40;
}
__device__ __forceinline__ void load8(const void* base, size_t idx, int isbf, float* f) {
    if (isbf) {
        uint4 v = *(const uint4*)((const u16*)base + idx);
        f[0] = bf2f(v.x & 0xffffu); f[1] = bf2f(v.x >> 16);
        f[2] = bf2f(v.y & 0xffffu); f[3] = bf2f(v.y >> 16);
        f[4] = bf2f(v.z & 0xffffu); f[5] = bf2f(v.z >> 16);
        f[6] = bf2f(v.w & 0xffffu); f[7] = bf2f(v.w >> 16);
    } else {
        const float* p = (const float*)base + idx;
        float4 a = *(const float4*)p;
        float4 b = *(const float4*)(p + 4);
        f[0] = a.x; f[1] = a.y; f[2] = a.z; f[3] = a.w;
        f[4] = b.x; f[5] = b.y; f[6] = b.z; f[7] = b.w;
    }
}
__device__ __forceinline__ float load1(const void* base, size_t idx, int isbf) {
    return isbf ? bf2f(((const u16*)base)[idx]) : ((const float*)base)[idx];
}
__device__ __forceinline__ void gld16(const u16* g, u16* l) {
    __builtin_amdgcn_global_load_lds(
        (const __attribute__((address_space(1))) void*)g,
        (__attribute__((address_space(3))) void*)l, 16, 0, 0);
}

// ---------------- prep1: weights+biases -> bf16 in ws, + dtype flag ---------
__global__ __launch_bounds__(256) void prep1(
    const void* w0, const void* w1, const void* w2,
    const void* b0, const void* b1, const void* b2, u16* wb)
{
    const int z = blockIdx.y;
    const void* w = (z == 0) ? w0 : (z == 1) ? w1 : w2;
    const void* bb = (z == 0) ? b0 : (z == 1) ? b1 : b2;
    const int isbf = detect_bf16(w0);
    const size_t idx = ((size_t)blockIdx.x * 256 + threadIdx.x) * 8;
    float f[8];
    load8(w, idx, isbf, f);
    union { u16 h[8]; uint4 v; } pk;
#pragma unroll
    for (int j = 0; j < 8; ++j) pk.h[j] = f2bf_bits(f[j]);
    *(uint4*)(wb + (size_t)z * 262144 + idx) = pk.v;
    if (blockIdx.x == 0) {
        u16* bbase = wb + 3 * 262144 + z * 512;
#pragma unroll
        for (int j = 0; j < 2; ++j) {
            int i = threadIdx.x * 2 + j;
            bbase[i] = f2bf_bits(load1(bb, i, isbf));
        }
        if (z == 0 && threadIdx.x == 0)
            *(int*)((char*)wb + FLAG_B) = isbf;
    }
}

// ---------------- shared frag+mfma step on staged LDS tiles -----------------
__device__ __forceinline__ void frag_mfma_step(
    const u16* As, const u16* Bs, int wm, int wn, int lane15, int quad,
    float4v acc[4][4])
{
    short8 af[4], bf[4];
#pragma unroll
    for (int mi = 0; mi < 4; ++mi) {
        const int r = wm * 64 + mi * 16 + lane15;
        af[mi] = *(const short8*)&As[(4 * r + (quad ^ ((r >> 1) & 3))) * 8];
    }
#pragma unroll
    for (int ni = 0; ni < 4; ++ni) {
        const int r = wn * 64 + ni * 16 + lane15;
        bf[ni] = *(const short8*)&Bs[(4 * r + (quad ^ ((r >> 1) & 3))) * 8];
    }
#pragma unroll
    for (int mi = 0; mi < 4; ++mi)
#pragma unroll
        for (int ni = 0; ni < 4; ++ni)
            acc[mi][ni] = mfma16(af[mi], bf[ni], acc[mi][ni]);
}

// ---------------- GEMM core: 128x128xBK32, m97 2-barrier loop (R7) ----------
__device__ __forceinline__ void gemm_core(
    const u16* __restrict__ A, int sA, const u16* __restrict__ B, int sB, int K,
    u16* As, u16* Bs, float4v acc[4][4])
{
    const int t = threadIdx.x;
    const int w = t >> 6, l = t & 63;
    const int lane15 = l & 15, quad = l >> 4;
    const int wm = w & 1, wn = w >> 1;

    for (int kt = 0; kt < K; kt += 32) {
        __syncthreads();
#pragma unroll
        for (int i = 0; i < 2; ++i) {
            const int fg = w * 128 + i * 64 + l;
            const int r = fg >> 2;
            const int kq = (fg & 3) ^ ((r >> 1) & 3);
            gld16(A + (size_t)r * sA + kt + kq * 8, As + fg * 8);
            gld16(B + (size_t)r * sB + kt + kq * 8, Bs + fg * 8);
        }
        __syncthreads();
        frag_mfma_step(As, Bs, wm, wn, lane15, quad, acc);
    }
}

// per-wave LDS redistribution -> coalesced stores (R7 proven, barriers)
__device__ __forceinline__ void store_tile_bf16(
    u16 (*Ts)[40], const u16 vals[4][4][4],
    int lane15, int quad, u16* gbase, size_t rstride)
{
#pragma unroll
    for (int h = 0; h < 2; ++h) {
#pragma unroll
        for (int mi = 0; mi < 4; ++mi)
#pragma unroll
            for (int nn = 0; nn < 2; ++nn)
#pragma unroll
                for (int r = 0; r < 4; ++r)
                    Ts[mi * 16 + quad * 4 + r][nn * 16 + lane15] =
                        vals[mi][2 * h + nn][r];
        __syncthreads();
#pragma unroll
        for (int mi = 0; mi < 4; ++mi) {
            uint4 v = *(const uint4*)&Ts[mi * 16 + lane15][quad * 8];
            *(uint4*)(gbase + (size_t)(mi * 16 + lane15) * rstride +
                      h * 32 + quad * 8) = v;
        }
        __syncthreads();
    }
}

#define GEMM_IDS()                                                  \
    const int t = threadIdx.x;                                      \
    const int w = t >> 6, l = t & 63; (void)l;                      \
    const int lane15 = l & 15, quad = l >> 4;                       \
    const int wm = w & 1, wn = w >> 1;

// ---------------- gemm_g: G' = Wk^T·Wq (transposed staging), u, v, c --------
// grid 18 blocks: 0..15 = G' 128x128 tiles; 16 = u (+c); 17 = v.
__global__ __launch_bounds__(256) void gemm_g(
    const void* __restrict__ wq, const void* __restrict__ wk,
    const void* __restrict__ bq, const void* __restrict__ bk,
    char* __restrict__ ws)
{
    const int isbf = *(const volatile int*)(ws + FLAG_B);
    const int bid = blockIdx.x;
    GEMM_IDS();

    if (bid >= 16) {
        // u[e] = sum_f Wq[f][e]*bk[f] (bid 16); v[e] = sum_f Wk[f][e]*bq[f] (17)
        const void* W  = (bid == 16) ? wq : wk;
        const void* bv = (bid == 16) ? bk : bq;
        float* dst = (float*)(ws + ((bid == 16) ? U_B : V_B));
        float a0 = 0.f, a1 = 0.f;
#pragma unroll 8
        for (int f = 0; f < 512; ++f) {
            const float bfv = load1(bv, f, isbf);
            a0 += bfv * load1(W, (size_t)f * 512 + t, isbf);
            a1 += bfv * load1(W, (size_t)f * 512 + t + 256, isbf);
        }
        dst[t] = a0; dst[t + 256] = a1;
        if (bid == 16 && t < 64) {      // c = bq·bk via wave 0
            float cc = 0.f;
            for (int f = t; f < 512; f += 64)
                cc += load1(bq, f, isbf) * load1(bk, f, isbf);
            cc += __shfl_xor(cc, 1, 64);  cc += __shfl_xor(cc, 2, 64);
            cc += __shfl_xor(cc, 4, 64);  cc += __shfl_xor(cc, 8, 64);
            cc += __shfl_xor(cc, 16, 64); cc += __shfl_xor(cc, 32, 64);
            if (t == 0) *(float*)(ws + C_B) = cc;
        }
        return;
    }

    __shared__ u16 As[4096] __attribute__((aligned(16)));
    __shared__ u16 Bs[4096] __attribute__((aligned(16)));
    __shared__ u16 Ts[4][64][40];

    const int tep = (bid >> 2) * 128;   // e' tile (rows of G')
    const int te  = (bid & 3) * 128;    // e tile (cols)

    float4v acc[4][4];
#pragma unroll
    for (int mi = 0; mi < 4; ++mi)
#pragma unroll
        for (int ni = 0; ni < 4; ++ni) acc[mi][ni] = (float4v){0.f, 0.f, 0.f, 0.f};

    const int f_loc = t >> 3;            // 0..31
    const int e_base = (t & 7) * 16;     // 0..112
    for (int kt = 0; kt < 512; kt += 32) {
        __syncthreads();
        float fa[16], fb[16];
        load8(wk, (size_t)(kt + f_loc) * 512 + tep + e_base,     isbf, fa);
        load8(wk, (size_t)(kt + f_loc) * 512 + tep + e_base + 8, isbf, fa + 8);
        load8(wq, (size_t)(kt + f_loc) * 512 + te + e_base,      isbf, fb);
        load8(wq, (size_t)(kt + f_loc) * 512 + te + e_base + 8,  isbf, fb + 8);
#pragma unroll
        for (int j = 0; j < 16; ++j) {
            const int r = e_base + j;
            const int g = 4 * r + ((f_loc >> 3) ^ ((r >> 1) & 3));
            As[g * 8 + (f_loc & 7)] = f2bf_bits(fa[j]);
            Bs[g * 8 + (f_loc & 7)] = f2bf_bits(fb[j]);
        }
        __syncthreads();
        frag_mfma_step(As, Bs, wm, wn, lane15, quad, acc);
    }

    u16 vals[4][4][4];
#pragma unroll
    for (int mi = 0; mi < 4; ++mi)
#pragma unroll
        for (int ni = 0; ni < 4; ++ni)
#pragma unroll
            for (int r = 0; r < 4; ++r)
                vals[mi][ni][r] = f2bf_bits(acc[mi][ni][r]);
    u16* gp = (u16*)(ws + GP_B);
    store_tile_bf16(Ts[w], vals, lane15, quad,
                    gp + (size_t)(tep + wm * 64) * 512 + te + wn * 64,
                    (size_t)512);
}

// ---------------- prep2: x conv + r/s; big mode also mask bits --------------
// grid: 4096 (+4096 mask blocks in big mode)
__global__ __launch_bounds__(256) void prep2(
    void* xbuf, char* ws, const int* __restrict__ mask, u32* __restrict__ bits,
    int do_bits)
{
    const int isbf = *(const volatile int*)(ws + FLAG_B);
    const int bid = blockIdx.x;
    const int t = threadIdx.x;

    if (bid >= 4096) {                       // mask bits (big mode only)
        const size_t widx = (size_t)(bid - 4096) * 256 + t;
        const int* src = mask + widx * 32;
        u32 v = 0;
#pragma unroll
        for (int j = 0; j < 32; j += 4) {
            int4 m4 = *(const int4*)(src + j);
            v |= (u32)(m4.x > 0) << j;
            v |= (u32)(m4.y > 0) << (j + 1);
            v |= (u32)(m4.z > 0) << (j + 2);
            v |= (u32)(m4.w > 0) << (j + 3);
        }
        bits[widx] = v;
        return;
    }

    const int w = t >> 6, l = t & 63;
    const int row = bid * 4 + w;
    float f[8];
    load8(xbuf, (size_t)row * 512 + l * 8, isbf, f);
    if (!isbf) {                             // fp32 -> bf16 lead halves
        union { u16 h[8]; uint4 v; } pk;
#pragma unroll
        for (int j = 0; j < 8; ++j) pk.h[j] = f2bf_bits(f[j]);
        *(uint4*)((u16*)xbuf + (size_t)row * 1024 + l * 8) = pk.v;
    }
    const float* u = (const float*)(ws + U_B);
    const float* v = (const float*)(ws + V_B);
    float4 u0 = *(const float4*)(u + l * 8), u1 = *(const float4*)(u + l * 8 + 4);
    float4 v0 = *(const float4*)(v + l * 8), v1 = *(const float4*)(v + l * 8 + 4);
    float rl = f[0]*u0.x + f[1]*u0.y + f[2]*u0.z + f[3]*u0.w
             + f[4]*u1.x + f[5]*u1.y + f[6]*u1.z + f[7]*u1.w;
    float sl = f[0]*v0.x + f[1]*v0.y + f[2]*v0.z + f[3]*v0.w
             + f[4]*v1.x + f[5]*v1.y + f[6]*v1.z + f[7]*v1.w;
#pragma unroll
    for (int d = 1; d < 64; d <<= 1) {
        rl += __shfl_xor(rl, d, 64);
        sl += __shfl_xor(sl, d, 64);
    }
    if (l == 0) {
        ((float*)(ws + R_B))[row] = rl + *(const float*)(ws + C_B);
        ((float*)(ws + SS_B))[row] = sl;
    }
}

// ---------------- mask_compress (small mode only, after proj) ---------------
__global__ __launch_bounds__(256) void mask_compress(
    const int* __restrict__ mask, u32* __restrict__ bits, const int* flagp)
{
    if (*flagp) return;                      // bf16-small: no destination
    const size_t widx = (size_t)blockIdx.x * 256 + threadIdx.x;
    const int* src = mask + widx * 32;
    u32 v = 0;
#pragma unroll
    for (int j = 0; j < 32; j += 4) {
        int4 m4 = *(const int4*)(src + j);
        v |= (u32)(m4.x > 0) << j;
        v |= (u32)(m4.y > 0) << (j + 1);
        v |= (u32)(m4.z > 0) << (j + 2);
        v |= (u32)(m4.w > 0) << (j + 3);
    }
    bits[widx] = v;
}

// ---------------- proj: big: z0=XG, z1=Vt ; small: z0=Q, z1=K, z2=Vt --------
__global__ __launch_bounds__(256) void proj_gemm(
    const void* __restrict__ xorig, char* __restrict__ ws, int big,
    u16* __restrict__ qb, u16* __restrict__ kb, int sQK, u16* __restrict__ vt)
{
    __shared__ u16 As[4096] __attribute__((aligned(16)));
    __shared__ u16 Bs[4096] __attribute__((aligned(16)));
    __shared__ u16 Ts[4][64][40];
    GEMM_IDS();

    const int z = blockIdx.z;
    const int isbf = *(const volatile int*)(ws + FLAG_B);
    const u16* wb = (const u16*)ws;
    const u16* xb = (const u16*)xorig;
    const int sx = isbf ? 512 : 1024;
    const int is_vt = big ? (z == 1) : (z == 2);

    int m0, n0; const u16 *A, *B; int sA, sB;
    float bcol[4], brow[4][4];

    if (is_vt) {
        m0 = blockIdx.x * 128; n0 = blockIdx.y * 128;
        A = wb + (size_t)2 * 262144 + (size_t)m0 * 512; sA = 512;
        B = xb + (size_t)n0 * sx; sB = sx;
        const u16* bias = wb + 3 * 262144 + 2 * 512;
#pragma unroll
        for (int mi = 0; mi < 4; ++mi)
#pragma unroll
            for (int r = 0; r < 4; ++r)
                brow[mi][r] = bf2f(bias[m0 + wm * 64 + mi * 16 + quad * 4 + r]);
    } else {
        m0 = blockIdx.y * 128; n0 = blockIdx.x * 128;
        A = xb + (size_t)m0 * sx; sA = sx;
        if (big) {  // z0: B = G' (bf16), no bias
            B = (const u16*)(ws + GP_B) + (size_t)n0 * 512; sB = 512;
#pragma unroll
            for (int ni = 0; ni < 4; ++ni) bcol[ni] = 0.f;
        } else {
            B = wb + (size_t)z * 262144 + (size_t)n0 * 512; sB = 512;
            const u16* bias = wb + 3 * 262144 + z * 512;
#pragma unroll
            for (int ni = 0; ni < 4; ++ni)
                bcol[ni] = bf2f(bias[n0 + wn * 64 + ni * 16 + lane15]);
        }
    }

    float4v acc[4][4];
#pragma unroll
    for (int mi = 0; mi < 4; ++mi)
#pragma unroll
        for (int ni = 0; ni < 4; ++ni) acc[mi][ni] = (float4v){0.f, 0.f, 0.f, 0.f};

    gemm_core(A, sA, B, sB, 512, As, Bs, acc);

    u16 vals[4][4][4];
    if (!is_vt) {
#pragma unroll
        for (int mi = 0; mi < 4; ++mi)
#pragma unroll
            for (int ni = 0; ni < 4; ++ni)
#pragma unroll
                for (int r = 0; r < 4; ++r)
                    vals[mi][ni][r] = f2bf_bits(acc[mi][ni][r] + bcol[ni]);
        u16* dst = (z ? kb : qb);
        store_tile_bf16(Ts[w], vals, lane15, quad,
                        dst + (size_t)(m0 + wm * 64) * sQK + n0 + wn * 64,
                        (size_t)sQK);
    } else {
#pragma unroll
        for (int mi = 0; mi < 4; ++mi)
#pragma unroll
            for (int ni = 0; ni < 4; ++ni)
#pragma unroll
                for (int r = 0; r < 4; ++r)
                    vals[mi][ni][r] = f2bf_bits(acc[mi][ni][r] + brow[mi][r]);
        const int b = n0 >> 11, tok0 = n0 & 2047;
        store_tile_bf16(Ts[w], vals, lane15, quad,
                        vt + (size_t)b * E_DIM * S_DIM +
                        (size_t)(m0 + wm * 64) * S_DIM + tok0 + wn * 64,
                        (size_t)S_DIM);
    }
}

// ---------------- gemmS ----------------
// big: A=XG(sA=512), B=xb(stride sx), +r/s epilogue. small: A=Q,B=K, plain.
__global__ __launch_bounds__(256) void gemmS(
    const u16* __restrict__ qb, int sQK, const u16* __restrict__ Bbase, int sBp,
    int use_rsc, char* __restrict__ ws,
    const int* __restrict__ mask, const u32* __restrict__ bits, int bits_mode,
    u16* sx_base, u16* sws_base, int nx, float* __restrict__ spart)
{
    __shared__ u16 As[4096] __attribute__((aligned(16)));
    __shared__ u16 Bs[4096] __attribute__((aligned(16)));
    __shared__ u32 Ms[128][4];
    __shared__ u16 Ts[4][64][40];
    __shared__ float Rred[128];
    GEMM_IDS();

    const int isbf = *(const volatile int*)(ws + FLAG_B);
    const int b = blockIdx.z, m0 = blockIdx.y * 128, ng = blockIdx.x;
    const int use_bits = (bits_mode == 2) || (bits_mode == 1 && !isbf);
    const int sB = use_rsc ? (isbf ? 512 : 1024) : sBp;
    const u16* A = qb + (size_t)(b * S_DIM + m0) * sQK;
    u16* Sb = (b < nx) ? (sx_base + (size_t)b * S_DIM * S_DIM)
                       : (sws_base + (size_t)(b - nx) * S_DIM * S_DIM);

    // r/s prefetch (big mode)
    float rr[4][4] = {}, c0 = 0.f;
    const float* rbuf = (const float*)(ws + R_B);
    const float* sbuf = (const float*)(ws + SS_B);
    if (use_rsc) {
#pragma unroll
        for (int mi = 0; mi < 4; ++mi)
#pragma unroll
            for (int r = 0; r < 4; ++r)
                rr[mi][r] = rbuf[b * S_DIM + m0 + wm * 64 + mi * 16 + quad * 4 + r];
    }
    (void)c0;

    float rsum[4][4] = {};

    for (int nt = 0; nt < 2; ++nt) {
        const int n0 = ng * 256 + nt * 128;
        __syncthreads();
        if (use_bits && t < 128)
            gld16((const u16*)(bits + ((size_t)(b * S_DIM + m0 + t) * 64) + (n0 >> 5)),
                  (u16*)&Ms[t][0]);

        float scol[4];
        if (use_rsc) {
#pragma unroll
            for (int ni = 0; ni < 4; ++ni)
                scol[ni] = sbuf[b * S_DIM + n0 + wn * 64 + ni * 16 + lane15];
        } else {
#pragma unroll
            for (int ni = 0; ni < 4; ++ni) scol[ni] = 0.f;
        }

        const u16* B = Bbase + (size_t)(b * S_DIM + n0) * sB;
        float4v acc[4][4];
#pragma unroll
        for (int mi = 0; mi < 4; ++mi)
#pragma unroll
            for (int ni = 0; ni < 4; ++ni) acc[mi][ni] = (float4v){0.f, 0.f, 0.f, 0.f};

        gemm_core(A, sQK, B, sB, 512, As, Bs, acc);

        u16 vals[4][4][4];
#pragma unroll
        for (int mi = 0; mi < 4; ++mi)
#pragma unroll
            for (int r = 0; r < 4; ++r) {
                const int rloc = wm * 64 + mi * 16 + quad * 4 + r;
                u32 w0 = 0, w1 = 0;
                int mkraw[4];
                if (use_bits) {
                    uint2 mw = *(const uint2*)&Ms[rloc][wn * 2];
                    w0 = mw.x; w1 = mw.y;
                } else {
#pragma unroll
                    for (int ni = 0; ni < 4; ++ni)
                        mkraw[ni] = mask[((size_t)b * S_DIM + m0 + rloc) * S_DIM +
                                         n0 + wn * 64 + ni * 16 + lane15];
                }
#pragma unroll
                for (int ni = 0; ni < 4; ++ni) {
                    int masked;
                    if (use_bits) {
                        const u32 word = (ni >> 1) ? w1 : w0;
                        masked = (word >> (((ni & 1) << 4) | lane15)) & 1;
                    } else masked = (mkraw[ni] > 0);
                    float pre = acc[mi][ni][r];
                    if (use_rsc) pre += rr[mi][r] + scol[ni];
                    const float p = masked ? 0.f : __expf(pre * SCALE);
                    const u16 hv = f2bf_bits(p);
                    vals[mi][ni][r] = hv;
                    rsum[mi][r] += bf2f(hv);
                }
            }
        store_tile_bf16(Ts[w], vals, lane15, quad,
                        Sb + (size_t)(m0 + wm * 64) * S_DIM + n0 + wn * 64,
                        (size_t)S_DIM);
    }

    // rowsum partials (butterfly under full exec — R7-fixed)
    float vred[4][4];
#pragma unroll
    for (int mi = 0; mi < 4; ++mi)
#pragma unroll
        for (int r = 0; r < 4; ++r) {
            float v = rsum[mi][r];
            v += __shfl_xor(v, 1, 64);
            v += __shfl_xor(v, 2, 64);
            v += __shfl_xor(v, 4, 64);
            v += __shfl_xor(v, 8, 64);
            vred[mi][r] = v;
            if (wn == 0 && lane15 == 0)
                Rred[wm * 64 + mi * 16 + quad * 4 + r] = v;
        }
    __syncthreads();
    if (wn == 1 && lane15 == 0) {
#pragma unroll
        for (int mi = 0; mi < 4; ++mi)
#pragma unroll
            for (int r = 0; r < 4; ++r) {
                const int rloc = wm * 64 + mi * 16 + quad * 4 + r;
                spart[((size_t)b * S_DIM + m0 + rloc) * 8 + ng] =
                    Rred[rloc] + vred[mi][r];
            }
    }
}

// ---------------- gemmO: out = (S @ Vt) / rowtot (rowsum inlined) -----------
__global__ __launch_bounds__(256) void gemmO(
    const u16* sx_base, const u16* sws_base, int nx,
    const u16* __restrict__ vt, const float* __restrict__ spart,
    float* __restrict__ outp)
{
    __shared__ u16 As[4096] __attribute__((aligned(16)));
    __shared__ u16 Bs[4096] __attribute__((aligned(16)));
    __shared__ float Rtot[128];
    GEMM_IDS();

    const int b = blockIdx.z;
    const int m0 = blockIdx.y * 128, n0 = blockIdx.x * 128;
    const u16* Sb = (b < nx) ? (sx_base + (size_t)b * S_DIM * S_DIM)
                             : (sws_base + (size_t)(b - nx) * S_DIM * S_DIM);
    const u16* A = Sb + (size_t)m0 * S_DIM;
    const u16* B = vt + ((size_t)b * E_DIM + n0) * S_DIM;

    if (t < 128) {
        const float* sp = spart + ((size_t)b * S_DIM + m0 + t) * 8;
        float4 a = *(const float4*)sp;
        float4 bb = *(const float4*)(sp + 4);
        Rtot[t] = a.x + a.y + a.z + a.w + bb.x + bb.y + bb.z + bb.w;
    }

    float4v acc[4][4];
#pragma unroll
    for (int mi = 0; mi < 4; ++mi)
#pragma unroll
        for (int ni = 0; ni < 4; ++ni) acc[mi][ni] = (float4v){0.f, 0.f, 0.f, 0.f};

    gemm_core(A, S_DIM, B, S_DIM, S_DIM, As, Bs, acc);

#pragma unroll
    for (int mi = 0; mi < 4; ++mi)
#pragma unroll
        for (int r = 0; r < 4; ++r) {
            const int rloc = wm * 64 + mi * 16 + quad * 4 + r;
            const int row = m0 + rloc;
            const float inv = 1.f / Rtot[rloc];
#pragma unroll
            for (int ni = 0; ni < 4; ++ni)
                outp[((size_t)b * S_DIM + row) * E_DIM + n0 + wn * 64 +
                     ni * 16 + lane15] = acc[mi][ni][r] * inv;
        }
}

extern "C" void kernel_launch(void* const* d_in, const int* in_sizes, int n_in,
                              void* d_out, int out_size, void* d_ws, size_t ws_size,
                              hipStream_t stream) {
    const void* x    = d_in[0];
    const int*  mask = (const int*)d_in[1];
    const void* wq   = d_in[2];
    const void* bq   = d_in[3];
    const void* wk   = d_in[4];
    const void* bk   = d_in[5];
    const void* wv   = d_in[6];
    const void* bv   = d_in[7];

    const size_t QSZ_B   = (size_t)NROWS * E_DIM * 2;        // 16.8 MB
    const size_t S_PB_B  = (size_t)S_DIM * S_DIM * 2;        // 8.39 MB
    const size_t SPART_B = (size_t)NROWS * 8 * 4;            // 512 KB
    const size_t BITS_B  = (size_t)8 * S_DIM * 64 * 4;       // 4.2 MB
    const size_t BIG_NEED = PREP_B + QSZ_B + QSZ_B + SPART_B +
                            8 * S_PB_B + BITS_B;             // ~109.4 MB

    char* ws = (char*)d_ws;
    const int* flagp = (const int*)(ws + FLAG_B);
    char* p = ws + PREP_B;

    u16 *qb, *kb, *vtb, *sws; float* spart; u32* bits;
    u16* sx_base = (u16*)x;
    int sQK, nx, bits_mode, big;

    if (ws_size >= BIG_NEED) {
        big = 1;
        qb  = (u16*)p;              p += QSZ_B;      // XG
        kb  = nullptr;
        vtb = (u16*)p;              p += QSZ_B;
        spart = (float*)p;          p += SPART_B;
        sws = (u16*)p;              p += 8 * S_PB_B;
        bits = (u32*)p;
        sQK = 512; nx = 0; bits_mode = 2;
    } else {
        big = 0;
        qb  = (u16*)d_out;                           // Q, lead halves
        kb  = (u16*)d_out + 512;                     // K, trail halves
        vtb = (u16*)p;              p += QSZ_B;
        spart = (float*)p;          p += SPART_B;
        sws = (u16*)p;
        bits = (u32*)((char*)x + 2 * S_PB_B);        // fp32 mode only
        sQK = 1024; nx = 2; bits_mode = 1;
    }

    prep1<<<dim3(128, 3), 256, 0, stream>>>(wq, wk, wv, bq, bk, bv, (u16*)ws);

    if (big)
        gemm_g<<<18, 256, 0, stream>>>(wq, wk, bq, bk, ws);

    prep2<<<big ? 8192 : 4096, 256, 0, stream>>>((void*)x, ws, mask, bits, big);

    proj_gemm<<<dim3(4, 128, big ? 2 : 3), 256, 0, stream>>>(
        x, ws, big, qb, kb, sQK, vtb);

    if (!big)
        mask_compress<<<4096, 256, 0, stream>>>(mask, bits, flagp);

    const u16* gemmS_B = big ? (const u16*)x : kb;
    gemmS<<<dim3(8, 16, 8), 256, 0, stream>>>(
        qb, sQK, gemmS_B, sQK, big, ws, mask, bits, bits_mode,
        sx_base, sws, nx, spart);

    gemmO<<<dim3(4, 16, 8), 256, 0, stream>>>(sx_base, sws, nx, vtb, spart,
                                              (float*)d_out);
}

// Round 10
// 476.147 us; speedup vs baseline: 1.0745x; 1.0163x over previous
//
#include <hip/hip_runtime.h>
#include <hip/hip_bf16.h>

// MHAHead B=8,S=2048,E=512. R10: lean 5-launch R5 structure + XCD-locality
// swizzled 1D grids (blocks sharing an A-tile are 128 apart == same XCD).
// Raw mask read inside latency-bound gemmS (free); no bits, no G-trick,
// no LDS store-redistribution (16.5 KB LDS).

typedef unsigned short u16;
typedef __attribute__((ext_vector_type(8))) short short8;
typedef __attribute__((ext_vector_type(4))) float float4v;

#define S_DIM 2048
#define E_DIM 512
#define NROWS (8 * S_DIM)
#define SCALE 0.044194173824159216f
#define FLAG_B 1575936        // bytes: after 3 weights + 3 biases (bf16)

__device__ __forceinline__ float4v mfma16(short8 a, short8 b, float4v c) {
    return __builtin_amdgcn_mfma_f32_16x16x32_bf16(a, b, c, 0, 0, 0);
}
__device__ __forceinline__ float bf2f(unsigned int u) {
    union { unsigned int i; float f; } v; v.i = u << 16; return v.f;
}
__device__ __forceinline__ u16 f2bf_bits(float f) {
    __hip_bfloat16 h = __float2bfloat16(f);
    return *(u16*)&h;
}
__device__ __forceinline__ int detect_bf16(const void* wp) {
    const u16* w = (const u16*)wp;
    int cnt = 0;
    for (int i = 0; i < 64; ++i) {
        int e = (w[2 * i] >> 7) & 0xff;
        cnt += (e >= 100 && e <= 131) ? 1 : 0;
    }
    return cnt >= 40;
}
__device__ __forceinline__ void load8(const void* base, size_t idx, int isbf, float* f) {
    if (isbf) {
        uint4 v = *(const uint4*)((const u16*)base + idx);
        f[0] = bf2f(v.x & 0xffffu); f[1] = bf2f(v.x >> 16);
        f[2] = bf2f(v.y & 0xffffu); f[3] = bf2f(v.y >> 16);
        f[4] = bf2f(v.z & 0xffffu); f[5] = bf2f(v.z >> 16);
        f[6] = bf2f(v.w & 0xffffu); f[7] = bf2f(v.w >> 16);
    } else {
        const float* p = (const float*)base + idx;
        float4 a = *(const float4*)p;
        float4 b = *(const float4*)(p + 4);
        f[0] = a.x; f[1] = a.y; f[2] = a.z; f[3] = a.w;
        f[4] = b.x; f[5] = b.y; f[6] = b.z; f[7] = b.w;
    }
}
__device__ __forceinline__ float load1(const void* base, size_t idx, int isbf) {
    return isbf ? bf2f(((const u16*)base)[idx]) : ((const float*)base)[idx];
}
__device__ __forceinline__ void gld16(const u16* g, u16* l) {
    __builtin_amdgcn_global_load_lds(
        (const __attribute__((address_space(1))) void*)g,
        (__attribute__((address_space(3))) void*)l, 16, 0, 0);
}

// ---------------- conv_w: weights+biases -> bf16 in ws, dtype flag ----------
__global__ __launch_bounds__(256) void conv_w(
    const void* w0, const void* w1, const void* w2,
    const void* b0, const void* b1, const void* b2, u16* wb)
{
    const int z = blockIdx.y;
    const void* w = (z == 0) ? w0 : (z == 1) ? w1 : w2;
    const void* bb = (z == 0) ? b0 : (z == 1) ? b1 : b2;
    const int isbf = detect_bf16(w0);
    const size_t idx = ((size_t)blockIdx.x * 256 + threadIdx.x) * 8;
    float f[8];
    load8(w, idx, isbf, f);
    union { u16 h[8]; uint4 v; } pk;
#pragma unroll
    for (int j = 0; j < 8; ++j) pk.h[j] = f2bf_bits(f[j]);
    *(uint4*)(wb + (size_t)z * 262144 + idx) = pk.v;
    if (blockIdx.x == 0) {
        u16* bbase = wb + 3 * 262144 + z * 512;
#pragma unroll
        for (int j = 0; j < 2; ++j) {
            int i = threadIdx.x * 2 + j;
            bbase[i] = f2bf_bits(load1(bb, i, isbf));
        }
        if (z == 0 && threadIdx.x == 0)
            *(int*)((char*)wb + FLAG_B) = isbf;
    }
}

// ---------------- conv_x: x fp32 -> bf16 lead halves ----------------
__global__ __launch_bounds__(256) void conv_x(void* xbuf, const int* flagp) {
    if (*flagp) return;
    const int w = threadIdx.x >> 6, l = threadIdx.x & 63;
    const int row = blockIdx.x * 4 + w;
    const float* src = (const float*)xbuf + (size_t)row * E_DIM + l * 8;
    float4 a = *(const float4*)src;
    float4 b = *(const float4*)(src + 4);
    union { u16 h[8]; uint4 v; } pk;
    pk.h[0] = f2bf_bits(a.x); pk.h[1] = f2bf_bits(a.y);
    pk.h[2] = f2bf_bits(a.z); pk.h[3] = f2bf_bits(a.w);
    pk.h[4] = f2bf_bits(b.x); pk.h[5] = f2bf_bits(b.y);
    pk.h[6] = f2bf_bits(b.z); pk.h[7] = f2bf_bits(b.w);
    *(uint4*)((u16*)xbuf + (size_t)row * 1024 + l * 8) = pk.v;
}

// ---------------- GEMM core: 128x128xBK32, m97 2-barrier K-loop -------------
__device__ __forceinline__ void gemm_core(
    const u16* __restrict__ A, int sA, const u16* __restrict__ B, int sB, int K,
    u16* As, u16* Bs, float4v acc[4][4])
{
    const int t = threadIdx.x;
    const int w = t >> 6, l = t & 63;
    const int lane15 = l & 15, quad = l >> 4;
    const int wm = w & 1, wn = w >> 1;

    for (int kt = 0; kt < K; kt += 32) {
        __syncthreads();
#pragma unroll
        for (int i = 0; i < 2; ++i) {
            const int fg = w * 128 + i * 64 + l;
            const int r = fg >> 2;
            const int kq = (fg & 3) ^ ((r >> 1) & 3);
            gld16(A + (size_t)r * sA + kt + kq * 8, As + fg * 8);
            gld16(B + (size_t)r * sB + kt + kq * 8, Bs + fg * 8);
        }
        __syncthreads();

        short8 af[4], bf[4];
#pragma unroll
        for (int mi = 0; mi < 4; ++mi) {
            const int r = wm * 64 + mi * 16 + lane15;
            af[mi] = *(const short8*)&As[(4 * r + (quad ^ ((r >> 1) & 3))) * 8];
        }
#pragma unroll
        for (int ni = 0; ni < 4; ++ni) {
            const int r = wn * 64 + ni * 16 + lane15;
            bf[ni] = *(const short8*)&Bs[(4 * r + (quad ^ ((r >> 1) & 3))) * 8];
        }
#pragma unroll
        for (int mi = 0; mi < 4; ++mi)
#pragma unroll
            for (int ni = 0; ni < 4; ++ni)
                acc[mi][ni] = mfma16(af[mi], bf[ni], acc[mi][ni]);
    }
}

#define GEMM_IDS()                                                  \
    const int t = threadIdx.x;                                      \
    const int w = t >> 6, l = t & 63; (void)l;                      \
    const int lane15 = l & 15, quad = l >> 4;                       \
    const int wm = w & 1, wn = w >> 1;

// ---------------- proj: z0=Q, z1=K, z2=Vt; grid (128, 4, 3), m fastest ------
__global__ __launch_bounds__(256) void proj_gemm(
    const void* __restrict__ xorig, const int* flagp,
    const u16* __restrict__ wb,
    u16* __restrict__ qb, u16* __restrict__ kb, int sQK, u16* __restrict__ vt)
{
    __shared__ u16 As[4096] __attribute__((aligned(16)));
    __shared__ u16 Bs[4096] __attribute__((aligned(16)));
    GEMM_IDS();

    const int z = blockIdx.z;
    const int isbf = *(const volatile int*)flagp;
    const u16* xb = (const u16*)xorig;
    const int sx = isbf ? 512 : 1024;
    const u16* bias = wb + 3 * 262144 + z * 512;

    int m0, n0; const u16 *A, *B; int sA, sB;
    if (z < 2) {    // rows = tokens (x fastest), cols = out-features (y)
        m0 = blockIdx.x * 128; n0 = blockIdx.y * 128;
        A = xb + (size_t)m0 * sx; sA = sx;
        B = wb + (size_t)z * 262144 + (size_t)n0 * 512; sB = 512;
    } else {        // Vt: rows = e (y), cols = tokens (x fastest)
        m0 = blockIdx.y * 128; n0 = blockIdx.x * 128;
        A = wb + (size_t)2 * 262144 + (size_t)m0 * 512; sA = 512;
        B = xb + (size_t)n0 * sx; sB = sx;
    }

    float bcol[4], brow[4][4];
    if (z < 2) {
#pragma unroll
        for (int ni = 0; ni < 4; ++ni)
            bcol[ni] = bf2f(bias[n0 + wn * 64 + ni * 16 + lane15]);
    } else {
#pragma unroll
        for (int mi = 0; mi < 4; ++mi)
#pragma unroll
            for (int r = 0; r < 4; ++r)
                brow[mi][r] = bf2f(bias[m0 + wm * 64 + mi * 16 + quad * 4 + r]);
    }

    float4v acc[4][4];
#pragma unroll
    for (int mi = 0; mi < 4; ++mi)
#pragma unroll
        for (int ni = 0; ni < 4; ++ni) acc[mi][ni] = (float4v){0.f, 0.f, 0.f, 0.f};

    gemm_core(A, sA, B, sB, 512, As, Bs, acc);

    if (z < 2) {
        u16* dst = (z ? kb : qb);
#pragma unroll
        for (int mi = 0; mi < 4; ++mi)
#pragma unroll
            for (int ni = 0; ni < 4; ++ni)
#pragma unroll
                for (int r = 0; r < 4; ++r) {
                    const int row = m0 + wm * 64 + mi * 16 + quad * 4 + r;
                    const int col = n0 + wn * 64 + ni * 16 + lane15;
                    dst[(size_t)row * sQK + col] = f2bf_bits(acc[mi][ni][r] + bcol[ni]);
                }
    } else {
#pragma unroll
        for (int mi = 0; mi < 4; ++mi)
#pragma unroll
            for (int r = 0; r < 4; ++r) {
                const int e = m0 + wm * 64 + mi * 16 + quad * 4 + r;
#pragma unroll
                for (int ni = 0; ni < 4; ++ni) {
                    const int tok = n0 + wn * 64 + ni * 16 + lane15;
                    vt[((size_t)(tok >> 11) * E_DIM + e) * S_DIM + (tok & 2047)] =
                        f2bf_bits(acc[mi][ni][r] + brow[mi][r]);
                }
            }
    }
}

// ---------------- gemmS: 1D grid 1024; bid = ng*128 + (b*16+mt) -------------
// All 8 ng sharing one A-tile are 128 apart -> same XCD -> A L2-resident.
// Raw mask read in epilogue (hidden by latency-bound loop). 2 n-tiles/block.
__global__ __launch_bounds__(256) void gemmS(
    const u16* __restrict__ qb, int sQK, const u16* __restrict__ kb, int sKB,
    const int* __restrict__ mask,
    u16* sx_base, u16* sws_base, int nx, float* __restrict__ spart)
{
    __shared__ u16 As[4096] __attribute__((aligned(16)));
    __shared__ u16 Bs[4096] __attribute__((aligned(16)));
    __shared__ float Rred[128];
    GEMM_IDS();

    const int bid = blockIdx.x;
    const int ng = bid >> 7;           // 0..7
    const int bm = bid & 127;
    const int b = bm >> 4, m0 = (bm & 15) * 128;

    const u16* A = qb + (size_t)(b * S_DIM + m0) * sQK;
    u16* Sb = (b < nx) ? (sx_base + (size_t)b * S_DIM * S_DIM)
                       : (sws_base + (size_t)(b - nx) * S_DIM * S_DIM);

    float rsum[4][4] = {};

    for (int nt = 0; nt < 2; ++nt) {
        const int n0 = ng * 256 + nt * 128;
        const u16* B = kb + (size_t)(b * S_DIM + n0) * sKB;

        float4v acc[4][4];
#pragma unroll
        for (int mi = 0; mi < 4; ++mi)
#pragma unroll
            for (int ni = 0; ni < 4; ++ni) acc[mi][ni] = (float4v){0.f, 0.f, 0.f, 0.f};

        gemm_core(A, sQK, B, sKB, 512, As, Bs, acc);

#pragma unroll
        for (int mi = 0; mi < 4; ++mi)
#pragma unroll
            for (int r = 0; r < 4; ++r) {
                const int rloc = wm * 64 + mi * 16 + quad * 4 + r;
                const int row = m0 + rloc;
                int mk[4];
#pragma unroll
                for (int ni = 0; ni < 4; ++ni)
                    mk[ni] = mask[((size_t)b * S_DIM + row) * S_DIM +
                                  n0 + wn * 64 + ni * 16 + lane15];
#pragma unroll
                for (int ni = 0; ni < 4; ++ni) {
                    const float p = (mk[ni] > 0) ? 0.f
                                                 : __expf(acc[mi][ni][r] * SCALE);
                    const u16 hv = f2bf_bits(p);
                    Sb[(size_t)row * S_DIM + n0 + wn * 64 + ni * 16 + lane15] = hv;
                    rsum[mi][r] += bf2f(hv);
                }
            }
    }

    // rowsum partials: butterfly under full exec, then cross-wave via LDS
    float vred[4][4];
#pragma unroll
    for (int mi = 0; mi < 4; ++mi)
#pragma unroll
        for (int r = 0; r < 4; ++r) {
            float v = rsum[mi][r];
            v += __shfl_xor(v, 1, 64);
            v += __shfl_xor(v, 2, 64);
            v += __shfl_xor(v, 4, 64);
            v += __shfl_xor(v, 8, 64);
            vred[mi][r] = v;
            if (wn == 0 && lane15 == 0)
                Rred[wm * 64 + mi * 16 + quad * 4 + r] = v;
        }
    __syncthreads();
    if (wn == 1 && lane15 == 0) {
#pragma unroll
        for (int mi = 0; mi < 4; ++mi)
#pragma unroll
            for (int r = 0; r < 4; ++r) {
                const int rloc = wm * 64 + mi * 16 + quad * 4 + r;
                spart[((size_t)b * S_DIM + m0 + rloc) * 8 + ng] =
                    Rred[rloc] + vred[mi][r];
            }
    }
}

// ---------------- gemmO: 1D grid 512; bid = nt*128 + (b*16+mt) --------------
// The 4 nt sharing one A-tile (512 KB of S rows) land on the same XCD.
__global__ __launch_bounds__(256) void gemmO(
    const u16* sx_base, const u16* sws_base, int nx,
    const u16* __restrict__ vt, const float* __restrict__ spart,
    float* __restrict__ outp)
{
    __shared__ u16 As[4096] __attribute__((aligned(16)));
    __shared__ u16 Bs[4096] __attribute__((aligned(16)));
    __shared__ float Rtot[128];
    GEMM_IDS();

    const int bid = blockIdx.x;
    const int ntile = bid >> 7;        // 0..3 (e-tile)
    const int bm = bid & 127;
    const int b = bm >> 4, m0 = (bm & 15) * 128;
    const int n0 = ntile * 128;

    const u16* Sb = (b < nx) ? (sx_base + (size_t)b * S_DIM * S_DIM)
                             : (sws_base + (size_t)(b - nx) * S_DIM * S_DIM);
    const u16* A = Sb + (size_t)m0 * S_DIM;
    const u16* B = vt + ((size_t)b * E_DIM + n0) * S_DIM;

    if (t < 128) {
        const float* sp = spart + ((size_t)b * S_DIM + m0 + t) * 8;
        float4 a = *(const float4*)sp;
        float4 bb = *(const float4*)(sp + 4);
        Rtot[t] = a.x + a.y + a.z + a.w + bb.x + bb.y + bb.z + bb.w;
    }

    float4v acc[4][4];
#pragma unroll
    for (int mi = 0; mi < 4; ++mi)
#pragma unroll
        for (int ni = 0; ni < 4; ++ni) acc[mi][ni] = (float4v){0.f, 0.f, 0.f, 0.f};

    gemm_core(A, S_DIM, B, S_DIM, S_DIM, As, Bs, acc);

#pragma unroll
    for (int mi = 0; mi < 4; ++mi)
#pragma unroll
        for (int r = 0; r < 4; ++r) {
            const int rloc = wm * 64 + mi * 16 + quad * 4 + r;
            const float inv = 1.f / Rtot[rloc];
#pragma unroll
            for (int ni = 0; ni < 4; ++ni)
                outp[((size_t)b * S_DIM + m0 + rloc) * E_DIM + n0 + wn * 64 +
                     ni * 16 + lane15] = acc[mi][ni][r] * inv;
        }
}

extern "C" void kernel_launch(void* const* d_in, const int* in_sizes, int n_in,
                              void* d_out, int out_size, void* d_ws, size_t ws_size,
                              hipStream_t stream) {
    const void* x    = d_in[0];
    const int*  mask = (const int*)d_in[1];
    const void* wq   = d_in[2];
    const void* bq   = d_in[3];
    const void* wk   = d_in[4];
    const void* bk   = d_in[5];
    const void* wv   = d_in[6];
    const void* bv   = d_in[7];

    const size_t MB      = 1u << 20;
    const size_t QSZ_B   = (size_t)NROWS * E_DIM * 2;        // 16.8 MB
    const size_t S_PB_B  = (size_t)S_DIM * S_DIM * 2;        // 8.39 MB
    const size_t SPART_B = (size_t)NROWS * 8 * 4;            // 512 KB
    const size_t BIG_NEED = 2 * MB + 3 * QSZ_B + SPART_B + 8 * S_PB_B;  // ~120 MB

    u16* wb = (u16*)d_ws;
    const int* flagp = (const int*)((char*)d_ws + FLAG_B);
    char* p = (char*)d_ws + 2 * MB;

    u16 *qb, *kb, *vtb, *sws; float* spart;
    u16* sx_base = (u16*)x;
    int sQK, sKB, nx;

    if (ws_size >= BIG_NEED) {
        qb  = (u16*)p;              p += QSZ_B;
        kb  = (u16*)p;              p += QSZ_B;
        vtb = (u16*)p;              p += QSZ_B;
        spart = (float*)p;          p += SPART_B;
        sws = (u16*)p;
        sQK = 512; sKB = 512; nx = 0;
    } else {
        qb  = (u16*)d_out;                           // Q lead halves
        kb  = (u16*)d_out + 512;                     // K trail halves
        vtb = (u16*)p;              p += QSZ_B;
        spart = (float*)p;          p += SPART_B;
        sws = (u16*)p;
        sQK = 1024; sKB = 1024; nx = 2;              // 2 S-batches over dead x
    }

    conv_w<<<dim3(128, 3), 256, 0, stream>>>(wq, wk, wv, bq, bk, bv, wb);
    conv_x<<<NROWS / 4, 256, 0, stream>>>((void*)x, flagp);

    proj_gemm<<<dim3(128, 4, 3), 256, 0, stream>>>(x, flagp, wb, qb, kb, sQK, vtb);

    gemmS<<<1024, 256, 0, stream>>>(qb, sQK, kb, sKB, mask,
                                    sx_base, sws, nx, spart);

    gemmO<<<512, 256, 0, stream>>>(sx_base, sws, nx, vtb, spart,
                                   (float*)d_out);
}